// Round 4
// baseline (145.588 us; speedup 1.0000x reference)
//
#include <hip/hip_runtime.h>
#include <hip/hip_bf16.h>
#include <hip/hip_cooperative_groups.h>

namespace cg = cooperative_groups;

#define MM 512
#define LL 31
#define LDB 15
#define NPIX (MM*MM)
#define NOUT (NPIX*LDB)
#define NBLK1 (NPIX/256)   // 1024 blocks

// ---- compile-time resize weight table (jax.image.resize linear, antialias) ----
struct WTab { float w[LDB][5]; int i0[LDB]; };

constexpr WTab make_wtab() {
    WTab t{};
    const double inv_scale = 31.0 / 15.0;
    const double ks = inv_scale;
    for (int k = 0; k < LDB; ++k) {
        double sf = (k + 0.5) * inv_scale - 0.5;
        double wv[LL] = {};
        double wsum = 0.0;
        for (int i = 0; i < LL; ++i) {
            double d = sf - (double)i;
            if (d < 0) d = -d;
            double w = 1.0 - d / ks;
            if (w < 0) w = 0;
            wv[i] = w;
            wsum += w;
        }
        int first = 0;
        while (first < LL && wv[first] == 0.0) ++first;
        t.i0[k] = first;
        for (int j = 0; j < 5; ++j) {
            int i = first + j;
            t.w[k][j] = (i < LL) ? (float)(wv[i] / wsum) : 0.0f;
        }
    }
    return t;
}

__constant__ WTab c_wtab = make_wtab();

__device__ __forceinline__ unsigned int enc_f32(float f) {
    unsigned int b = __float_as_uint(f);
    return (b & 0x80000000u) ? ~b : (b | 0x80000000u);
}
__device__ __forceinline__ float dec_f32(unsigned int u) {
    unsigned int b = (u & 0x80000000u) ? (u & 0x7fffffffu) : ~u;
    return __uint_as_float(b);
}

#define XTILE_F  (256*LL)            // 7936 floats = 31.75 KB
#define XTILE_V4 (XTILE_F/4)         // 1984
#define HTILE_F  (256*LDB)           // 3840 floats
#define HTILE_V4 (HTILE_F/4)         // 960

// =================== fused cooperative kernel ===================
__global__ __launch_bounds__(256) void fused_k(const float* __restrict__ X,
                                               const float* __restrict__ y,
                                               const float* __restrict__ H,
                                               float4* __restrict__ out4,
                                               float* __restrict__ partials) {
    __shared__ float lds[XTILE_F];          // X tile, then reused: H tile [0,3840) + r [3840,4096)
    __shared__ float redbuf[4];
    __shared__ float s_inv;
    float4* lds4 = (float4*)lds;

    const int tid = threadIdx.x;
    const int bid = blockIdx.x;
    const int p   = bid * 256 + tid;

    float yv = y[p];   // issue early, coalesced

    // ---- stage X tile (256 px * 31 bands), coalesced float4 ----
    {
        const float4* X4 = (const float4*)(X + (size_t)bid * XTILE_F);
#pragma unroll
        for (int j = 0; j < 7; ++j)
            lds4[j * 256 + tid] = X4[j * 256 + tid];
        if (tid < XTILE_V4 - 7 * 256)
            lds4[7 * 256 + tid] = X4[7 * 256 + tid];
    }
    __syncthreads();

    float xv[LL];
#pragma unroll
    for (int i = 0; i < LL; ++i) xv[i] = lds[tid * LL + i];

    float xr[LDB];
#pragma unroll
    for (int k = 0; k < LDB; ++k) {
        int i0 = c_wtab.i0[k];
        float s = 0.f;
#pragma unroll
        for (int j = 0; j < 5; ++j) {
            int i = i0 + j;
            if (i > LL - 1) i = LL - 1;   // weight 0 there; clamp keeps index in-bounds
            s += c_wtab.w[k][j] * xv[i];
        }
        xr[k] = s;
    }
    __syncthreads();   // X reads done before overwriting with H

    // ---- stage H tile (256 px * 15 bands) ----
    {
        const float4* H4 = (const float4*)(H + (size_t)bid * HTILE_F);
#pragma unroll
        for (int j = 0; j < 3; ++j)
            lds4[j * 256 + tid] = H4[j * 256 + tid];
        if (tid < HTILE_V4 - 3 * 256)
            lds4[3 * 256 + tid] = H4[3 * 256 + tid];
    }
    __syncthreads();

    float s = 0.f, hmin = 1e30f, hmax = -1e30f;
#pragma unroll
    for (int k = 0; k < LDB; ++k) {
        float h = lds[tid * LDB + k];
        s += h * xr[k];
        hmin = fminf(hmin, h);
        hmax = fmaxf(hmax, h);
    }
    float r = s - yv;

    lds[HTILE_F + tid] = r;   // park r for the write phase (read after grid sync)

    // per-pixel max of H*r over k (H >= 0): r>0 ? r*hmax : r*hmin
    float m = (r > 0.f) ? r * hmax : r * hmin;
#pragma unroll
    for (int off = 32; off; off >>= 1) m = fmaxf(m, __shfl_xor(m, off));
    if ((tid & 63) == 0) redbuf[tid >> 6] = m;
    __syncthreads();
    if (tid == 0) {
        float bm = fmaxf(fmaxf(redbuf[0], redbuf[1]), fmaxf(redbuf[2], redbuf[3]));
        // agent-scope store: bypasses the non-coherent per-XCD L2
        __hip_atomic_store(&partials[bid], bm, __ATOMIC_RELEASE, __HIP_MEMORY_SCOPE_AGENT);
    }

    cg::this_grid().sync();

    // ---- every block reduces all 1024 partials (coalesced agent-scope loads) ----
    float m2 = -1e30f;
#pragma unroll
    for (int j = 0; j < NBLK1 / 256; ++j)
        m2 = fmaxf(m2, __hip_atomic_load(&partials[j * 256 + tid],
                                         __ATOMIC_RELAXED, __HIP_MEMORY_SCOPE_AGENT));
#pragma unroll
    for (int off = 32; off; off >>= 1) m2 = fmaxf(m2, __shfl_xor(m2, off));
    if ((tid & 63) == 0) redbuf[tid >> 6] = m2;
    __syncthreads();
    if (tid == 0)
        s_inv = 1.0f / fmaxf(fmaxf(redbuf[0], redbuf[1]), fmaxf(redbuf[2], redbuf[3]));
    __syncthreads();
    const float inv = s_inv;

    // ---- write phase: out = H * r * inv, straight from LDS, float4 coalesced ----
    // block owns float4s [bid*960, bid*960+960); local flat index == pix*15+band
#pragma unroll
    for (int j = 0; j < 4; ++j) {
        int q = j * 256 + tid;               // 0..959 (j==3: tid<192)
        if (j == 3 && tid >= HTILE_V4 - 3 * 256) break;
        float4 h = lds4[q];                  // contiguous H values
        int f0 = q * 4;
        int pl0 = f0 / LDB;
        int rm  = f0 - pl0 * LDB;
        int pl1 = pl0 + 1; if (pl1 > 255) pl1 = 255;
        float rv0 = lds[HTILE_F + pl0] * inv;
        float rv1 = lds[HTILE_F + pl1] * inv;
        float4 o;
        o.x = h.x * ((rm + 0 < LDB) ? rv0 : rv1);
        o.y = h.y * ((rm + 1 < LDB) ? rv0 : rv1);
        o.z = h.z * ((rm + 2 < LDB) ? rv0 : rv1);
        o.w = h.w * ((rm + 3 < LDB) ? rv0 : rv1);
        out4[(size_t)bid * HTILE_V4 + q] = o;
    }
}

// =================== fallback path (3 kernels, round-3 proven) ===================
template <bool ATOMIC_FALLBACK>
__global__ __launch_bounds__(256) void pass1_k(const float* __restrict__ X,
                                               const float* __restrict__ y,
                                               const float* __restrict__ H,
                                               float* __restrict__ r_or_xn,
                                               float* __restrict__ partials,
                                               unsigned int* __restrict__ gmax_atomic) {
    __shared__ float lds[XTILE_F];
    __shared__ float redbuf[4];
    float4* lds4 = (float4*)lds;

    const int tid = threadIdx.x;
    const int p   = blockIdx.x * 256 + tid;

    {
        const float4* X4 = (const float4*)(X + (size_t)blockIdx.x * XTILE_F);
#pragma unroll
        for (int j = 0; j < 7; ++j)
            lds4[j * 256 + tid] = X4[j * 256 + tid];
        if (tid < XTILE_V4 - 7 * 256)
            lds4[7 * 256 + tid] = X4[7 * 256 + tid];
    }
    __syncthreads();

    float xv[LL];
#pragma unroll
    for (int i = 0; i < LL; ++i) xv[i] = lds[tid * LL + i];

    float xr[LDB];
#pragma unroll
    for (int k = 0; k < LDB; ++k) {
        int i0 = c_wtab.i0[k];
        float s = 0.f;
#pragma unroll
        for (int j = 0; j < 5; ++j) {
            int i = i0 + j;
            if (i > LL - 1) i = LL - 1;
            s += c_wtab.w[k][j] * xv[i];
        }
        xr[k] = s;
    }
    __syncthreads();

    {
        const float4* H4 = (const float4*)(H + (size_t)blockIdx.x * HTILE_F);
#pragma unroll
        for (int j = 0; j < 3; ++j)
            lds4[j * 256 + tid] = H4[j * 256 + tid];
        if (tid < HTILE_V4 - 3 * 256)
            lds4[3 * 256 + tid] = H4[3 * 256 + tid];
    }
    __syncthreads();

    float s = 0.f, hmin = 1e30f, hmax = -1e30f;
#pragma unroll
    for (int k = 0; k < LDB; ++k) {
        float h = lds[tid * LDB + k];
        s += h * xr[k];
        hmin = fminf(hmin, h);
        hmax = fmaxf(hmax, h);
    }
    float r = s - y[p];

    if (ATOMIC_FALLBACK) {
        float* op = r_or_xn + (size_t)p * LDB;
#pragma unroll
        for (int k = 0; k < LDB; ++k) op[k] = lds[tid * LDB + k] * r;
    } else {
        r_or_xn[p] = r;
    }

    float m = (r > 0.f) ? r * hmax : r * hmin;
#pragma unroll
    for (int off = 32; off; off >>= 1) m = fmaxf(m, __shfl_xor(m, off));

    if (ATOMIC_FALLBACK) {
        if ((tid & 63) == 0) atomicMax(gmax_atomic, enc_f32(m));
    } else {
        if ((tid & 63) == 0) redbuf[tid >> 6] = m;
        __syncthreads();
        if (tid == 0)
            partials[blockIdx.x] =
                fmaxf(fmaxf(redbuf[0], redbuf[1]), fmaxf(redbuf[2], redbuf[3]));
    }
}

__global__ __launch_bounds__(256) void reduce_k(const float* __restrict__ partials,
                                                float* __restrict__ gmaxf) {
    __shared__ float rb[4];
    int tid = threadIdx.x;
    float m = -1e30f;
#pragma unroll
    for (int j = 0; j < NBLK1 / 256; ++j)
        m = fmaxf(m, partials[j * 256 + tid]);
#pragma unroll
    for (int off = 32; off; off >>= 1) m = fmaxf(m, __shfl_xor(m, off));
    if ((tid & 63) == 0) rb[tid >> 6] = m;
    __syncthreads();
    if (tid == 0)
        gmaxf[0] = fmaxf(fmaxf(rb[0], rb[1]), fmaxf(rb[2], rb[3]));
}

__global__ __launch_bounds__(256) void pass2_k(const float4* __restrict__ H4,
                                               const float* __restrict__ r_in,
                                               const float* __restrict__ gmaxf,
                                               float4* __restrict__ out4) {
    float inv = 1.0f / gmaxf[0];
    int i4 = blockIdx.x * 256 + threadIdx.x;
    int i0 = i4 * 4;

    float4 h = H4[i4];

    int p0 = i0 / LDB;
    int rm = i0 - p0 * LDB;
    int p1 = p0 + 1; if (p1 > NPIX - 1) p1 = NPIX - 1;
    float rv0 = r_in[p0] * inv;
    float rv1 = r_in[p1] * inv;

    float4 o;
    o.x = h.x * ((rm + 0 < LDB) ? rv0 : rv1);
    o.y = h.y * ((rm + 1 < LDB) ? rv0 : rv1);
    o.z = h.z * ((rm + 2 < LDB) ? rv0 : rv1);
    o.w = h.w * ((rm + 3 < LDB) ? rv0 : rv1);
    out4[i4] = o;
}

__global__ __launch_bounds__(256) void pass2_inplace_k(float* __restrict__ out,
                                                       const unsigned int* __restrict__ gmax) {
    float inv = 1.0f / dec_f32(*gmax);
    int idx = blockIdx.x * blockDim.x + threadIdx.x;
    if (idx >= NOUT) return;
    out[idx] *= inv;
}

extern "C" void kernel_launch(void* const* d_in, const int* in_sizes, int n_in,
                              void* d_out, int out_size, void* d_ws, size_t ws_size,
                              hipStream_t stream) {
    const float* X = (const float*)d_in[0];
    const float* y = (const float*)d_in[1];
    const float* H = (const float*)d_in[2];
    float* out = (float*)d_out;

    // ws layout: [0,256)=gmax  [256,256+4K)=partials  [256+4K, ...)=r_buf
    unsigned int* gmax_u = (unsigned int*)d_ws;
    float* gmax_f   = (float*)d_ws;
    float* partials = (float*)((char*)d_ws + 256);
    float* r_buf    = (float*)((char*)d_ws + 256 + NBLK1 * sizeof(float));

    const int blk = 256;
    const int g2v = (NOUT / 4) / blk;
    const int g2s = (NOUT + blk - 1) / blk;

    if (ws_size >= 256 + (size_t)NBLK1 * 4) {
        // ---- fast path: single cooperative kernel ----
        const float* Xa = X; const float* ya = y; const float* Ha = H;
        float4* o4 = (float4*)out;
        float* pa = partials;
        void* args[] = {(void*)&Xa, (void*)&ya, (void*)&Ha, (void*)&o4, (void*)&pa};
        hipError_t e = hipLaunchCooperativeKernel((const void*)fused_k,
                                                  dim3(NBLK1), dim3(blk), args, 0, stream);
        if (e == hipSuccess) return;
        // cooperative unavailable: fall through to 3-kernel path if ws allows
        if (ws_size >= 256 + (size_t)NBLK1 * 4 + (size_t)NPIX * 4) {
            pass1_k<false><<<NBLK1, blk, 0, stream>>>(X, y, H, r_buf, partials, gmax_u);
            reduce_k<<<1, blk, 0, stream>>>(partials, gmax_f);
            pass2_k<<<g2v, blk, 0, stream>>>((const float4*)H, r_buf, gmax_f, (float4*)out);
            return;
        }
    }

    // ---- minimal-ws fallback: atomic path ----
    hipMemsetAsync(d_ws, 0, 256, stream);
    pass1_k<true><<<NBLK1, blk, 0, stream>>>(X, y, H, out, partials, gmax_u);
    pass2_inplace_k<<<g2s, blk, 0, stream>>>(out, gmax_u);
}

// Round 6
// 20.902 us; speedup vs baseline: 6.9654x; 6.9654x over previous
//
#include <hip/hip_runtime.h>
#include <hip/hip_bf16.h>

#define MM 512
#define LL 31
#define LDB 15
#define NPIX (MM*MM)
#define NOUT (NPIX*LDB)
#define NBLK1 (NPIX/256)   // 1024 blocks, one 256-pixel tile each

typedef float f32x4 __attribute__((ext_vector_type(4)));   // native vec for nt-store

// ---- compile-time resize weight table (jax.image.resize linear, antialias) ----
struct WTab { float w[LDB][5]; int i0[LDB]; };

constexpr WTab make_wtab() {
    WTab t{};
    const double inv_scale = 31.0 / 15.0;
    const double ks = inv_scale;
    for (int k = 0; k < LDB; ++k) {
        double sf = (k + 0.5) * inv_scale - 0.5;
        double wv[LL] = {};
        double wsum = 0.0;
        for (int i = 0; i < LL; ++i) {
            double d = sf - (double)i;
            if (d < 0) d = -d;
            double w = 1.0 - d / ks;
            if (w < 0) w = 0;
            wv[i] = w;
            wsum += w;
        }
        int first = 0;
        while (first < LL && wv[first] == 0.0) ++first;
        t.i0[k] = first;
        for (int j = 0; j < 5; ++j) {
            int i = first + j;
            t.w[k][j] = (i < LL) ? (float)(wv[i] / wsum) : 0.0f;
        }
    }
    return t;
}

__constant__ WTab c_wtab = make_wtab();

__device__ __forceinline__ unsigned int enc_f32(float f) {
    unsigned int b = __float_as_uint(f);
    return (b & 0x80000000u) ? ~b : (b | 0x80000000u);
}
__device__ __forceinline__ float dec_f32(unsigned int u) {
    unsigned int b = (u & 0x80000000u) ? (u & 0x7fffffffu) : ~u;
    return __uint_as_float(b);
}

#define XTILE_F  (256*LL)            // 7936 floats = 31.75 KB
#define XTILE_V4 (XTILE_F/4)         // 1984
#define HTILE_F  (256*LDB)           // 3840 floats
#define HTILE_V4 (HTILE_F/4)         // 960

// ---- pass 1: r = sum_k H*Xr - y ; per-block max partial (no global atomics) ----
template <bool ATOMIC_FALLBACK>
__global__ __launch_bounds__(256) void pass1_k(const float* __restrict__ X,
                                               const float* __restrict__ y,
                                               const float* __restrict__ H,
                                               float* __restrict__ r_or_xn,
                                               float* __restrict__ partials,
                                               unsigned int* __restrict__ gmax_atomic) {
    __shared__ float lds[XTILE_F];
    __shared__ float redbuf[4];
    float4* lds4 = (float4*)lds;

    const int tid = threadIdx.x;
    const int p   = blockIdx.x * 256 + tid;   // grid exact: 1024*256 = NPIX

    float yv = y[p];

    // ---- stage X tile (256 px * 31 bands), coalesced float4 ----
    {
        const float4* X4 = (const float4*)(X + (size_t)blockIdx.x * XTILE_F);
#pragma unroll
        for (int j = 0; j < 7; ++j)
            lds4[j * 256 + tid] = X4[j * 256 + tid];
        if (tid < XTILE_V4 - 7 * 256)
            lds4[7 * 256 + tid] = X4[7 * 256 + tid];
    }
    __syncthreads();

    float xv[LL];
#pragma unroll
    for (int i = 0; i < LL; ++i) xv[i] = lds[tid * LL + i];

    float xr[LDB];
#pragma unroll
    for (int k = 0; k < LDB; ++k) {
        int i0 = c_wtab.i0[k];
        float s = 0.f;
#pragma unroll
        for (int j = 0; j < 5; ++j) {
            int i = i0 + j;
            if (i > LL - 1) i = LL - 1;   // weight 0 there; clamp keeps index in-bounds
            s += c_wtab.w[k][j] * xv[i];
        }
        xr[k] = s;
    }
    __syncthreads();   // X reads done before overwriting with H

    // ---- stage H tile ----
    {
        const float4* H4 = (const float4*)(H + (size_t)blockIdx.x * HTILE_F);
#pragma unroll
        for (int j = 0; j < 3; ++j)
            lds4[j * 256 + tid] = H4[j * 256 + tid];
        if (tid < HTILE_V4 - 3 * 256)
            lds4[3 * 256 + tid] = H4[3 * 256 + tid];
    }
    __syncthreads();

    float s = 0.f, hmin = 1e30f, hmax = -1e30f;
#pragma unroll
    for (int k = 0; k < LDB; ++k) {
        float h = lds[tid * LDB + k];
        s += h * xr[k];
        hmin = fminf(hmin, h);
        hmax = fmaxf(hmax, h);
    }
    float r = s - yv;

    if (ATOMIC_FALLBACK) {
        float* op = r_or_xn + (size_t)p * LDB;
#pragma unroll
        for (int k = 0; k < LDB; ++k) op[k] = lds[tid * LDB + k] * r;
    } else {
        r_or_xn[p] = r;
    }

    // per-pixel max of H*r over k (H >= 0): r>0 ? r*hmax : r*hmin
    float m = (r > 0.f) ? r * hmax : r * hmin;
#pragma unroll
    for (int off = 32; off; off >>= 1) m = fmaxf(m, __shfl_xor(m, off));

    if (ATOMIC_FALLBACK) {
        if ((tid & 63) == 0) atomicMax(gmax_atomic, enc_f32(m));
    } else {
        if ((tid & 63) == 0) redbuf[tid >> 6] = m;
        __syncthreads();
        if (tid == 0)
            partials[blockIdx.x] =
                fmaxf(fmaxf(redbuf[0], redbuf[1]), fmaxf(redbuf[2], redbuf[3]));
    }
}

// ---- pass 2: inline partials-reduce + out = H * r / max (tiled like pass1) ----
__global__ __launch_bounds__(256) void pass2_k(const float4* __restrict__ H4,
                                               const float* __restrict__ r_in,
                                               const float* __restrict__ partials,
                                               f32x4* __restrict__ out4) {
    __shared__ float lds_r[256];
    __shared__ float redbuf[4];
    __shared__ float s_inv;

    const int tid = threadIdx.x;
    const int bid = blockIdx.x;

    // stage this tile's r (coalesced, 1 load/thread)
    lds_r[tid] = r_in[bid * 256 + tid];

    // reduce the 1024 partials: 256 threads x 1 float4
    {
        const float4* p4 = (const float4*)partials;
        float4 v = p4[tid];
        float m = fmaxf(fmaxf(v.x, v.y), fmaxf(v.z, v.w));
#pragma unroll
        for (int off = 32; off; off >>= 1) m = fmaxf(m, __shfl_xor(m, off));
        if ((tid & 63) == 0) redbuf[tid >> 6] = m;
    }
    __syncthreads();
    if (tid == 0)
        s_inv = 1.0f / fmaxf(fmaxf(redbuf[0], redbuf[1]), fmaxf(redbuf[2], redbuf[3]));
    __syncthreads();
    const float inv = s_inv;

    // write 960 float4 of this tile: flat local index = pix*15 + band
    const float4* Ht = H4 + (size_t)bid * HTILE_V4;
    f32x4*        Ot = out4 + (size_t)bid * HTILE_V4;
#pragma unroll
    for (int j = 0; j < 4; ++j) {
        int q = j * 256 + tid;                 // 0..959 (j==3: only tid<192)
        if (j == 3 && tid >= HTILE_V4 - 3 * 256) break;
        float4 h = Ht[q];
        int f0 = q * 4;
        int pl0 = f0 / LDB;
        int rm  = f0 - pl0 * LDB;
        int pl1 = pl0 + 1; if (pl1 > 255) pl1 = 255;  // only hit when rm+3 < 15 anyway
        float rv0 = lds_r[pl0] * inv;
        float rv1 = lds_r[pl1] * inv;
        f32x4 o;
        o.x = h.x * ((rm + 0 < LDB) ? rv0 : rv1);
        o.y = h.y * ((rm + 1 < LDB) ? rv0 : rv1);
        o.z = h.z * ((rm + 2 < LDB) ? rv0 : rv1);
        o.w = h.w * ((rm + 3 < LDB) ? rv0 : rv1);
        __builtin_nontemporal_store(o, &Ot[q]);   // out is write-only; skip L2 pollution
    }
}

// ---- fallback: out *= 1/max in place (atomic path) ----
__global__ __launch_bounds__(256) void pass2_inplace_k(float* __restrict__ out,
                                                       const unsigned int* __restrict__ gmax) {
    float inv = 1.0f / dec_f32(*gmax);
    int idx = blockIdx.x * blockDim.x + threadIdx.x;
    if (idx >= NOUT) return;
    out[idx] *= inv;
}

extern "C" void kernel_launch(void* const* d_in, const int* in_sizes, int n_in,
                              void* d_out, int out_size, void* d_ws, size_t ws_size,
                              hipStream_t stream) {
    const float* X = (const float*)d_in[0];
    const float* y = (const float*)d_in[1];
    const float* H = (const float*)d_in[2];
    float* out = (float*)d_out;

    // ws layout: [0,256)=gmax  [256,256+4K)=partials  [256+4K, ...)=r_buf
    unsigned int* gmax_u  = (unsigned int*)d_ws;
    float* partials = (float*)((char*)d_ws + 256);
    float* r_buf    = (float*)((char*)d_ws + 256 + NBLK1 * sizeof(float));

    const int blk = 256;
    const int g2s = (NOUT + blk - 1) / blk;

    size_t need = 256 + (size_t)NBLK1 * 4 + (size_t)NPIX * 4;
    if (ws_size >= need) {
        pass1_k<false><<<NBLK1, blk, 0, stream>>>(X, y, H, r_buf, partials, gmax_u);
        pass2_k<<<NBLK1, blk, 0, stream>>>((const float4*)H, r_buf, partials, (f32x4*)out);
    } else {
        (void)hipMemsetAsync(d_ws, 0, 256, stream);
        pass1_k<true><<<NBLK1, blk, 0, stream>>>(X, y, H, out, partials, gmax_u);
        pass2_inplace_k<<<g2s, blk, 0, stream>>>(out, gmax_u);
    }
}

// Round 7
// 20.886 us; speedup vs baseline: 6.9706x; 1.0008x over previous
//
#include <hip/hip_runtime.h>
#include <hip/hip_bf16.h>

#define MM 512
#define LL 31
#define LDB 15
#define NPIX (MM*MM)
#define NOUT (NPIX*LDB)
#define NBLK1 (NPIX/256)   // 1024 blocks, one 256-pixel tile each
#define NPART (NBLK1*4)    // per-wave partials: 4096 floats

typedef float f32x4 __attribute__((ext_vector_type(4)));   // native vec for nt-store

// ---- compile-time resize weight table (jax.image.resize linear, antialias) ----
struct WTab { float w[LDB][5]; int i0[LDB]; };

constexpr WTab make_wtab() {
    WTab t{};
    const double inv_scale = 31.0 / 15.0;
    const double ks = inv_scale;
    for (int k = 0; k < LDB; ++k) {
        double sf = (k + 0.5) * inv_scale - 0.5;
        double wv[LL] = {};
        double wsum = 0.0;
        for (int i = 0; i < LL; ++i) {
            double d = sf - (double)i;
            if (d < 0) d = -d;
            double w = 1.0 - d / ks;
            if (w < 0) w = 0;
            wv[i] = w;
            wsum += w;
        }
        int first = 0;
        while (first < LL && wv[first] == 0.0) ++first;
        t.i0[k] = first;
        for (int j = 0; j < 5; ++j) {
            int i = first + j;
            t.w[k][j] = (i < LL) ? (float)(wv[i] / wsum) : 0.0f;
        }
    }
    return t;
}

__constant__ WTab c_wtab = make_wtab();

__device__ __forceinline__ unsigned int enc_f32(float f) {
    unsigned int b = __float_as_uint(f);
    return (b & 0x80000000u) ? ~b : (b | 0x80000000u);
}
__device__ __forceinline__ float dec_f32(unsigned int u) {
    unsigned int b = (u & 0x80000000u) ? (u & 0x7fffffffu) : ~u;
    return __uint_as_float(b);
}

#define XTILE_F  (256*LL)            // 7936 floats = 31.75 KB
#define XTILE_V4 (XTILE_F/4)         // 1984
#define HTILE_F  (256*LDB)           // 3840 floats
#define HTILE_V4 (HTILE_F/4)         // 960

// ---- pass 1: r = sum_k H*Xr - y ; per-WAVE max partial (no tail barriers) ----
template <bool ATOMIC_FALLBACK>
__global__ __launch_bounds__(256) void pass1_k(const float* __restrict__ X,
                                               const float* __restrict__ y,
                                               const float* __restrict__ H,
                                               float* __restrict__ r_or_xn,
                                               float* __restrict__ partials,
                                               unsigned int* __restrict__ gmax_atomic) {
    __shared__ float lds[XTILE_F];
    float4* lds4 = (float4*)lds;

    const int tid = threadIdx.x;
    const int p   = blockIdx.x * 256 + tid;   // grid exact: 1024*256 = NPIX

    float yv = y[p];

    // ---- stage X tile (256 px * 31 bands), coalesced float4 ----
    {
        const float4* X4 = (const float4*)(X + (size_t)blockIdx.x * XTILE_F);
#pragma unroll
        for (int j = 0; j < 7; ++j)
            lds4[j * 256 + tid] = X4[j * 256 + tid];
        if (tid < XTILE_V4 - 7 * 256)
            lds4[7 * 256 + tid] = X4[7 * 256 + tid];
    }
    __syncthreads();

    float xv[LL];
#pragma unroll
    for (int i = 0; i < LL; ++i) xv[i] = lds[tid * LL + i];

    float xr[LDB];
#pragma unroll
    for (int k = 0; k < LDB; ++k) {
        int i0 = c_wtab.i0[k];
        float s = 0.f;
#pragma unroll
        for (int j = 0; j < 5; ++j) {
            int i = i0 + j;
            if (i > LL - 1) i = LL - 1;   // weight 0 there; clamp keeps index in-bounds
            s += c_wtab.w[k][j] * xv[i];
        }
        xr[k] = s;
    }
    __syncthreads();   // X reads done before overwriting with H

    // ---- stage H tile ----
    {
        const float4* H4 = (const float4*)(H + (size_t)blockIdx.x * HTILE_F);
#pragma unroll
        for (int j = 0; j < 3; ++j)
            lds4[j * 256 + tid] = H4[j * 256 + tid];
        if (tid < HTILE_V4 - 3 * 256)
            lds4[3 * 256 + tid] = H4[3 * 256 + tid];
    }
    __syncthreads();

    float s = 0.f, hmin = 1e30f, hmax = -1e30f;
#pragma unroll
    for (int k = 0; k < LDB; ++k) {
        float h = lds[tid * LDB + k];
        s += h * xr[k];
        hmin = fminf(hmin, h);
        hmax = fmaxf(hmax, h);
    }
    float r = s - yv;

    if (ATOMIC_FALLBACK) {
        float* op = r_or_xn + (size_t)p * LDB;
#pragma unroll
        for (int k = 0; k < LDB; ++k) op[k] = lds[tid * LDB + k] * r;
    } else {
        r_or_xn[p] = r;
    }

    // per-pixel max of H*r over k (H >= 0): r>0 ? r*hmax : r*hmin
    float m = (r > 0.f) ? r * hmax : r * hmin;
#pragma unroll
    for (int off = 32; off; off >>= 1) m = fmaxf(m, __shfl_xor(m, off));

    if (ATOMIC_FALLBACK) {
        if ((tid & 63) == 0) atomicMax(gmax_atomic, enc_f32(m));
    } else {
        // per-wave partial: no block reduce, no extra barriers
        if ((tid & 63) == 0) partials[blockIdx.x * 4 + (tid >> 6)] = m;
    }
}

// ---- pass 2: overlapped partials-reduce + out = H * r / max (1 barrier) ----
__global__ __launch_bounds__(256) void pass2_k(const float4* __restrict__ H4,
                                               const float* __restrict__ r_in,
                                               const float* __restrict__ partials,
                                               f32x4* __restrict__ out4) {
    __shared__ float lds_r[256];
    __shared__ float redbuf[4];

    const int tid  = threadIdx.x;
    const int bid  = blockIdx.x;
    const int wv   = tid >> 6;
    const int lane = tid & 63;

    // ---- issue ALL loads up front so they overlap the reduce ----
    // partials slice for this wave: quarter = float4 [wv*256, wv*256+256)
    const float4* p4 = (const float4*)partials;        // NPART/4 = 1024 float4
    float4 a0 = p4[wv * 256 + lane];
    float4 a1 = p4[wv * 256 + 64 + lane];
    float4 a2 = p4[wv * 256 + 128 + lane];
    float4 a3 = p4[wv * 256 + 192 + lane];

    const float4* Ht = H4 + (size_t)bid * HTILE_V4;
    float4 h0 = Ht[tid];
    float4 h1 = Ht[256 + tid];
    float4 h2 = Ht[512 + tid];
    const bool has3 = tid < HTILE_V4 - 3 * 256;        // tid < 192
    float4 h3 = h0;
    if (has3) h3 = Ht[768 + tid];

    lds_r[tid] = r_in[bid * 256 + tid];

    // ---- per-wave reduce of this quarter (runs while H loads are in flight) ----
    float m = fmaxf(fmaxf(fmaxf(a0.x, a0.y), fmaxf(a0.z, a0.w)),
                    fmaxf(fmaxf(a1.x, a1.y), fmaxf(a1.z, a1.w)));
    m = fmaxf(m, fmaxf(fmaxf(a2.x, a2.y), fmaxf(a2.z, a2.w)));
    m = fmaxf(m, fmaxf(fmaxf(a3.x, a3.y), fmaxf(a3.z, a3.w)));
#pragma unroll
    for (int off = 32; off; off >>= 1) m = fmaxf(m, __shfl_xor(m, off));
    if (lane == 0) redbuf[wv] = m;
    __syncthreads();   // single barrier: covers redbuf AND lds_r
    const float inv =
        1.0f / fmaxf(fmaxf(redbuf[0], redbuf[1]), fmaxf(redbuf[2], redbuf[3]));

    // ---- emit: flat local index = pix*15 + band ----
    f32x4* Ot = out4 + (size_t)bid * HTILE_V4;
#define EMIT(hh, qq)                                                        \
    {                                                                       \
        int q = (qq);                                                       \
        int f0 = q * 4;                                                     \
        int pl0 = f0 / LDB;                                                 \
        int rm  = f0 - pl0 * LDB;                                           \
        int pl1 = pl0 + 1; if (pl1 > 255) pl1 = 255;                        \
        float rv0 = lds_r[pl0] * inv;                                       \
        float rv1 = lds_r[pl1] * inv;                                       \
        f32x4 o;                                                            \
        o.x = (hh).x * ((rm + 0 < LDB) ? rv0 : rv1);                        \
        o.y = (hh).y * ((rm + 1 < LDB) ? rv0 : rv1);                        \
        o.z = (hh).z * ((rm + 2 < LDB) ? rv0 : rv1);                        \
        o.w = (hh).w * ((rm + 3 < LDB) ? rv0 : rv1);                        \
        __builtin_nontemporal_store(o, &Ot[q]);                             \
    }
    EMIT(h0, tid);
    EMIT(h1, 256 + tid);
    EMIT(h2, 512 + tid);
    if (has3) EMIT(h3, 768 + tid);
#undef EMIT
}

// ---- fallback: out *= 1/max in place (atomic path) ----
__global__ __launch_bounds__(256) void pass2_inplace_k(float* __restrict__ out,
                                                       const unsigned int* __restrict__ gmax) {
    float inv = 1.0f / dec_f32(*gmax);
    int idx = blockIdx.x * blockDim.x + threadIdx.x;
    if (idx >= NOUT) return;
    out[idx] *= inv;
}

extern "C" void kernel_launch(void* const* d_in, const int* in_sizes, int n_in,
                              void* d_out, int out_size, void* d_ws, size_t ws_size,
                              hipStream_t stream) {
    const float* X = (const float*)d_in[0];
    const float* y = (const float*)d_in[1];
    const float* H = (const float*)d_in[2];
    float* out = (float*)d_out;

    // ws layout: [0,256)=gmax  [256, 256+16K)=partials(4096 f)  [256+16K, ...)=r_buf
    unsigned int* gmax_u  = (unsigned int*)d_ws;
    float* partials = (float*)((char*)d_ws + 256);
    float* r_buf    = (float*)((char*)d_ws + 256 + (size_t)NPART * sizeof(float));

    const int blk = 256;
    const int g2s = (NOUT + blk - 1) / blk;

    size_t need = 256 + (size_t)NPART * 4 + (size_t)NPIX * 4;
    if (ws_size >= need) {
        pass1_k<false><<<NBLK1, blk, 0, stream>>>(X, y, H, r_buf, partials, gmax_u);
        pass2_k<<<NBLK1, blk, 0, stream>>>((const float4*)H, r_buf, partials, (f32x4*)out);
    } else {
        (void)hipMemsetAsync(d_ws, 0, 256, stream);
        pass1_k<true><<<NBLK1, blk, 0, stream>>>(X, y, H, out, partials, gmax_u);
        pass2_inplace_k<<<g2s, blk, 0, stream>>>(out, gmax_u);
    }
}

// Round 8
// 19.489 us; speedup vs baseline: 7.4703x; 1.0717x over previous
//
#include <hip/hip_runtime.h>
#include <hip/hip_bf16.h>

#define MM 512
#define LL 31
#define LDB 15
#define NPIX (MM*MM)
#define NOUT (NPIX*LDB)
#define NBLK1 (NPIX/256)   // 1024 blocks, one 256-pixel tile each
#define NPART (NBLK1*4)    // per-wave partials: 4096 floats

typedef float f32x4 __attribute__((ext_vector_type(4)));   // native vec for nt-store

// ---- compile-time resize weight table (jax.image.resize linear, antialias) ----
struct WTab { float w[LDB][5]; int i0[LDB]; };

constexpr WTab make_wtab() {
    WTab t{};
    const double inv_scale = 31.0 / 15.0;
    const double ks = inv_scale;
    for (int k = 0; k < LDB; ++k) {
        double sf = (k + 0.5) * inv_scale - 0.5;
        double wv[LL] = {};
        double wsum = 0.0;
        for (int i = 0; i < LL; ++i) {
            double d = sf - (double)i;
            if (d < 0) d = -d;
            double w = 1.0 - d / ks;
            if (w < 0) w = 0;
            wv[i] = w;
            wsum += w;
        }
        int first = 0;
        while (first < LL && wv[first] == 0.0) ++first;
        t.i0[k] = first;
        for (int j = 0; j < 5; ++j) {
            int i = first + j;
            t.w[k][j] = (i < LL) ? (float)(wv[i] / wsum) : 0.0f;
        }
    }
    return t;
}

__constant__ WTab c_wtab = make_wtab();

__device__ __forceinline__ unsigned int enc_f32(float f) {
    unsigned int b = __float_as_uint(f);
    return (b & 0x80000000u) ? ~b : (b | 0x80000000u);
}
__device__ __forceinline__ float dec_f32(unsigned int u) {
    unsigned int b = (u & 0x80000000u) ? (u & 0x7fffffffu) : ~u;
    return __uint_as_float(b);
}

#define XTILE_F  (256*LL)            // 7936 floats = 31.75 KB
#define XTILE_V4 (XTILE_F/4)         // 1984
#define HTILE_F  (256*LDB)           // 3840 floats
#define HTILE_V4 (HTILE_F/4)         // 960

// async global->LDS, 16B per lane; LDS base must be wave-uniform, linear fill
__device__ __forceinline__ void async_cp16(const float4* g, const float4* l) {
    __builtin_amdgcn_global_load_lds(
        (const __attribute__((address_space(1))) void*)g,
        (__attribute__((address_space(3))) void*)l,
        16, 0, 0);
}

// ---- pass 1 (fast): single-barrier fully-async staging of X and H ----
__global__ __launch_bounds__(256) void pass1_async_k(const float* __restrict__ X,
                                                     const float* __restrict__ y,
                                                     const float* __restrict__ H,
                                                     float* __restrict__ r_out,
                                                     float* __restrict__ partials) {
    __shared__ float lds[XTILE_F + HTILE_F];   // [X: 7936][H: 3840] floats = 46 KB
    float4* lds4 = (float4*)lds;

    const int tid   = threadIdx.x;
    const int bid   = blockIdx.x;
    const int lane  = tid & 63;
    const int wbase = tid - lane;              // wave-uniform LDS anchor
    const int p     = bid * 256 + tid;

    const float4* X4g = (const float4*)(X + (size_t)bid * XTILE_F);
    const float4* H4g = (const float4*)(H + (size_t)bid * HTILE_F);

    // ---- issue ALL staging up front, fire-and-forget ----
#pragma unroll
    for (int j = 0; j < 7; ++j)
        async_cp16(&X4g[j * 256 + tid], &lds4[j * 256 + wbase]);
    if (tid < XTILE_V4 - 7 * 256)              // 192 = 3 full waves: wave-uniform
        async_cp16(&X4g[7 * 256 + tid], &lds4[7 * 256 + wbase]);
#pragma unroll
    for (int j = 0; j < 3; ++j)
        async_cp16(&H4g[j * 256 + tid], &lds4[XTILE_V4 + j * 256 + wbase]);
    if (tid < HTILE_V4 - 3 * 256)              // 192 = 3 full waves: wave-uniform
        async_cp16(&H4g[3 * 256 + tid], &lds4[XTILE_V4 + 3 * 256 + wbase]);

    float yv = y[p];

    __syncthreads();   // single barrier: drains vmcnt (all staging) for the block

    // ---- spectral resize from LDS (stride 31: odd -> conflict-free) ----
    float xv[LL];
#pragma unroll
    for (int i = 0; i < LL; ++i) xv[i] = lds[tid * LL + i];

    float xr[LDB];
#pragma unroll
    for (int k = 0; k < LDB; ++k) {
        int i0 = c_wtab.i0[k];
        float s = 0.f;
#pragma unroll
        for (int j = 0; j < 5; ++j) {
            int i = i0 + j;
            if (i > LL - 1) i = LL - 1;        // weight 0 there; clamp keeps index in-bounds
            s += c_wtab.w[k][j] * xv[i];
        }
        xr[k] = s;
    }

    // ---- sensing dot-product from H region (stride 15: odd -> conflict-free) ----
    const float* hl = lds + XTILE_F + tid * LDB;
    float s = 0.f, hmin = 1e30f, hmax = -1e30f;
#pragma unroll
    for (int k = 0; k < LDB; ++k) {
        float h = hl[k];
        s += h * xr[k];
        hmin = fminf(hmin, h);
        hmax = fmaxf(hmax, h);
    }
    float r = s - yv;

    r_out[p] = r;

    // per-pixel max of H*r over k (H >= 0): r>0 ? r*hmax : r*hmin
    float m = (r > 0.f) ? r * hmax : r * hmin;
#pragma unroll
    for (int off = 32; off; off >>= 1) m = fmaxf(m, __shfl_xor(m, off));
    if (lane == 0) partials[bid * 4 + (tid >> 6)] = m;   // per-wave partial, no tail barrier
}

// ---- pass 2: overlapped partials-reduce + out = H * r / max (1 barrier) ----
__global__ __launch_bounds__(256) void pass2_k(const float4* __restrict__ H4,
                                               const float* __restrict__ r_in,
                                               const float* __restrict__ partials,
                                               f32x4* __restrict__ out4) {
    __shared__ float lds_r[256];
    __shared__ float redbuf[4];

    const int tid  = threadIdx.x;
    const int bid  = blockIdx.x;
    const int wv   = tid >> 6;
    const int lane = tid & 63;

    // issue ALL loads up front so they overlap the reduce
    const float4* p4 = (const float4*)partials;        // NPART/4 = 1024 float4
    float4 a0 = p4[wv * 256 + lane];
    float4 a1 = p4[wv * 256 + 64 + lane];
    float4 a2 = p4[wv * 256 + 128 + lane];
    float4 a3 = p4[wv * 256 + 192 + lane];

    const float4* Ht = H4 + (size_t)bid * HTILE_V4;
    float4 h0 = Ht[tid];
    float4 h1 = Ht[256 + tid];
    float4 h2 = Ht[512 + tid];
    const bool has3 = tid < HTILE_V4 - 3 * 256;        // tid < 192
    float4 h3 = h0;
    if (has3) h3 = Ht[768 + tid];

    lds_r[tid] = r_in[bid * 256 + tid];

    float m = fmaxf(fmaxf(fmaxf(a0.x, a0.y), fmaxf(a0.z, a0.w)),
                    fmaxf(fmaxf(a1.x, a1.y), fmaxf(a1.z, a1.w)));
    m = fmaxf(m, fmaxf(fmaxf(a2.x, a2.y), fmaxf(a2.z, a2.w)));
    m = fmaxf(m, fmaxf(fmaxf(a3.x, a3.y), fmaxf(a3.z, a3.w)));
#pragma unroll
    for (int off = 32; off; off >>= 1) m = fmaxf(m, __shfl_xor(m, off));
    if (lane == 0) redbuf[wv] = m;
    __syncthreads();   // single barrier: covers redbuf AND lds_r
    const float inv =
        1.0f / fmaxf(fmaxf(redbuf[0], redbuf[1]), fmaxf(redbuf[2], redbuf[3]));

    f32x4* Ot = out4 + (size_t)bid * HTILE_V4;
#define EMIT(hh, qq)                                                        \
    {                                                                       \
        int q = (qq);                                                       \
        int f0 = q * 4;                                                     \
        int pl0 = f0 / LDB;                                                 \
        int rm  = f0 - pl0 * LDB;                                           \
        int pl1 = pl0 + 1; if (pl1 > 255) pl1 = 255;                        \
        float rv0 = lds_r[pl0] * inv;                                       \
        float rv1 = lds_r[pl1] * inv;                                       \
        f32x4 o;                                                            \
        o.x = (hh).x * ((rm + 0 < LDB) ? rv0 : rv1);                        \
        o.y = (hh).y * ((rm + 1 < LDB) ? rv0 : rv1);                        \
        o.z = (hh).z * ((rm + 2 < LDB) ? rv0 : rv1);                        \
        o.w = (hh).w * ((rm + 3 < LDB) ? rv0 : rv1);                        \
        __builtin_nontemporal_store(o, &Ot[q]);                             \
    }
    EMIT(h0, tid);
    EMIT(h1, 256 + tid);
    EMIT(h2, 512 + tid);
    if (has3) EMIT(h3, 768 + tid);
#undef EMIT
}

// =============== fallback path (atomic, minimal ws) ===============
__global__ __launch_bounds__(256) void pass1_atomic_k(const float* __restrict__ X,
                                                      const float* __restrict__ y,
                                                      const float* __restrict__ H,
                                                      float* __restrict__ xn_out,
                                                      unsigned int* __restrict__ gmax_atomic) {
    __shared__ float lds[XTILE_F];
    float4* lds4 = (float4*)lds;

    const int tid = threadIdx.x;
    const int p   = blockIdx.x * 256 + tid;

    float yv = y[p];

    {
        const float4* X4 = (const float4*)(X + (size_t)blockIdx.x * XTILE_F);
#pragma unroll
        for (int j = 0; j < 7; ++j)
            lds4[j * 256 + tid] = X4[j * 256 + tid];
        if (tid < XTILE_V4 - 7 * 256)
            lds4[7 * 256 + tid] = X4[7 * 256 + tid];
    }
    __syncthreads();

    float xv[LL];
#pragma unroll
    for (int i = 0; i < LL; ++i) xv[i] = lds[tid * LL + i];

    float xr[LDB];
#pragma unroll
    for (int k = 0; k < LDB; ++k) {
        int i0 = c_wtab.i0[k];
        float s = 0.f;
#pragma unroll
        for (int j = 0; j < 5; ++j) {
            int i = i0 + j;
            if (i > LL - 1) i = LL - 1;
            s += c_wtab.w[k][j] * xv[i];
        }
        xr[k] = s;
    }
    __syncthreads();

    {
        const float4* H4 = (const float4*)(H + (size_t)blockIdx.x * HTILE_F);
#pragma unroll
        for (int j = 0; j < 3; ++j)
            lds4[j * 256 + tid] = H4[j * 256 + tid];
        if (tid < HTILE_V4 - 3 * 256)
            lds4[3 * 256 + tid] = H4[3 * 256 + tid];
    }
    __syncthreads();

    float s = 0.f, hmin = 1e30f, hmax = -1e30f;
#pragma unroll
    for (int k = 0; k < LDB; ++k) {
        float h = lds[tid * LDB + k];
        s += h * xr[k];
        hmin = fminf(hmin, h);
        hmax = fmaxf(hmax, h);
    }
    float r = s - yv;

    float* op = xn_out + (size_t)p * LDB;
#pragma unroll
    for (int k = 0; k < LDB; ++k) op[k] = lds[tid * LDB + k] * r;

    float m = (r > 0.f) ? r * hmax : r * hmin;
#pragma unroll
    for (int off = 32; off; off >>= 1) m = fmaxf(m, __shfl_xor(m, off));
    if ((tid & 63) == 0) atomicMax(gmax_atomic, enc_f32(m));
}

__global__ __launch_bounds__(256) void pass2_inplace_k(float* __restrict__ out,
                                                       const unsigned int* __restrict__ gmax) {
    float inv = 1.0f / dec_f32(*gmax);
    int idx = blockIdx.x * blockDim.x + threadIdx.x;
    if (idx >= NOUT) return;
    out[idx] *= inv;
}

extern "C" void kernel_launch(void* const* d_in, const int* in_sizes, int n_in,
                              void* d_out, int out_size, void* d_ws, size_t ws_size,
                              hipStream_t stream) {
    const float* X = (const float*)d_in[0];
    const float* y = (const float*)d_in[1];
    const float* H = (const float*)d_in[2];
    float* out = (float*)d_out;

    // ws layout: [0,256)=gmax  [256, 256+16K)=partials(4096 f)  [256+16K, ...)=r_buf
    unsigned int* gmax_u  = (unsigned int*)d_ws;
    float* partials = (float*)((char*)d_ws + 256);
    float* r_buf    = (float*)((char*)d_ws + 256 + (size_t)NPART * sizeof(float));

    const int blk = 256;
    const int g2s = (NOUT + blk - 1) / blk;

    size_t need = 256 + (size_t)NPART * 4 + (size_t)NPIX * 4;
    if (ws_size >= need) {
        pass1_async_k<<<NBLK1, blk, 0, stream>>>(X, y, H, r_buf, partials);
        pass2_k<<<NBLK1, blk, 0, stream>>>((const float4*)H, r_buf, partials, (f32x4*)out);
    } else {
        (void)hipMemsetAsync(d_ws, 0, 256, stream);
        pass1_atomic_k<<<NBLK1, blk, 0, stream>>>(X, y, H, out, gmax_u);
        pass2_inplace_k<<<g2s, blk, 0, stream>>>(out, gmax_u);
    }
}